// Round 10
// baseline (253.223 us; speedup 1.0000x reference)
//
#include <hip/hip_runtime.h>
#include <math.h>

#define TN 2048            // T
#define NF 4096            // Bluestein FFT length
#define NB 64              // batch
#define LF 6142LL          // L = 3T-2
#define L2F 12284LL        // 2L
#define PI_D 3.14159265358979323846264338327950288
#define C8 0.70710678118654752440084436210485
#define K16A 0.92387953251128675612818318939678828682   // cos(pi/8)
#define K16B 0.38268343236508977172845998403039886676   // sin(pi/8)
#define C8f   0.70710678118654752440f
#define K16Af 0.92387953251128675613f
#define K16Bf 0.38268343236508977173f

typedef double2 cpx;
typedef float2 cf;

__device__ __forceinline__ cpx cmk(double a, double b){ cpx r; r.x=a; r.y=b; return r; }
__device__ __forceinline__ cpx cadd(cpx a, cpx b){ return cmk(a.x+b.x, a.y+b.y); }
__device__ __forceinline__ cpx csub(cpx a, cpx b){ return cmk(a.x-b.x, a.y-b.y); }
__device__ __forceinline__ cpx cmul(cpx a, cpx b){ return cmk(a.x*b.x - a.y*b.y, a.x*b.y + a.y*b.x); }
__device__ __forceinline__ cpx cmulc(cpx a, cpx b){ return cmk(a.x*b.x + a.y*b.y, a.y*b.x - a.x*b.y); } // a*conj(b)
__device__ __forceinline__ cf c2s(cpx a){ cf r; r.x=(float)a.x; r.y=(float)a.y; return r; }

__device__ __forceinline__ cf cfmk(float a, float b){ cf r; r.x=a; r.y=b; return r; }
__device__ __forceinline__ cf cfadd(cf a, cf b){ return cfmk(a.x+b.x, a.y+b.y); }
__device__ __forceinline__ cf cfsub(cf a, cf b){ return cfmk(a.x-b.x, a.y-b.y); }
__device__ __forceinline__ cf cfmul(cf a, cf b){ return cfmk(a.x*b.x - a.y*b.y, a.x*b.y + a.y*b.x); }
__device__ __forceinline__ cf cfmulc(cf a, cf b){ return cfmk(a.x*b.x + a.y*b.y, a.y*b.x - a.x*b.y); }

// fp64 twiddle on the fly: exp(-2*pi*i*idx/4096) — replaces the dead tw[] table
__device__ __forceinline__ cpx twd64(int idx){
  double s, c;
  sincos(-2.0 * PI_D * (double)idx / 4096.0, &s, &c);
  return cmk(c, s);
}

// LDS swizzle, element granularity — k_front chat (cpx) / k_fft_u (cf)
__device__ __forceinline__ int SW(int i){ return i ^ ((i >> 3) & 7) ^ ((i >> 6) & 7); }
// LDS swizzle, pair (16 B float4) granularity — k_czt. Involution; bank-ideal
// for stride 256/16/1 patterns (verified R7: conflicts 1.18M -> 36.9K).
__device__ __forceinline__ int SWP(int i){ return i ^ ((i >> 4) & 15) ^ ((i >> 8) & 15); }

// wave-local sync: fences compiler + drains lgkmcnt; no cross-wave lock-step
__device__ __forceinline__ void wsync(){
  __builtin_amdgcn_wave_barrier();
  asm volatile("s_waitcnt lgkmcnt(0)" ::: "memory");
  __builtin_amdgcn_wave_barrier();
}

// ---------- fp64 8/16-point register FFT (chat builder only)
__device__ __forceinline__ void fft8_bc(cpx* a){
  cpx u, v, d;
  u=a[0]; v=a[2]; a[0]=cadd(u,v); a[2]=csub(u,v);
  u=a[1]; v=a[3]; a[1]=cadd(u,v); d=csub(u,v); a[3]=cmk(d.y, -d.x);
  u=a[4]; v=a[6]; a[4]=cadd(u,v); a[6]=csub(u,v);
  u=a[5]; v=a[7]; a[5]=cadd(u,v); d=csub(u,v); a[7]=cmk(d.y, -d.x);
  u=a[0]; v=a[1]; a[0]=cadd(u,v); a[1]=csub(u,v);
  u=a[2]; v=a[3]; a[2]=cadd(u,v); a[3]=csub(u,v);
  u=a[4]; v=a[5]; a[4]=cadd(u,v); a[5]=csub(u,v);
  u=a[6]; v=a[7]; a[6]=cadd(u,v); a[7]=csub(u,v);
}
__device__ __forceinline__ void fft8(cpx* a){
  cpx u, v, d;
  u=a[0]; v=a[4]; a[0]=cadd(u,v); a[4]=csub(u,v);
  u=a[1]; v=a[5]; a[1]=cadd(u,v); d=csub(u,v); a[5]=cmk(C8*(d.x+d.y), C8*(d.y-d.x));
  u=a[2]; v=a[6]; a[2]=cadd(u,v); d=csub(u,v); a[6]=cmk(d.y, -d.x);
  u=a[3]; v=a[7]; a[3]=cadd(u,v); d=csub(u,v); a[7]=cmk(C8*(d.y-d.x), -C8*(d.x+d.y));
  fft8_bc(a);
}
__device__ __forceinline__ void fft16(cpx* a){
  cpx u, v, d;
  u=a[0]; v=a[8];  a[0]=cadd(u,v); a[8] = csub(u,v);
  u=a[1]; v=a[9];  a[1]=cadd(u,v); d=csub(u,v); a[9]  = cmk(K16A*d.x + K16B*d.y, K16A*d.y - K16B*d.x);
  u=a[2]; v=a[10]; a[2]=cadd(u,v); d=csub(u,v); a[10] = cmk(C8*(d.x+d.y), C8*(d.y-d.x));
  u=a[3]; v=a[11]; a[3]=cadd(u,v); d=csub(u,v); a[11] = cmk(K16B*d.x + K16A*d.y, K16B*d.y - K16A*d.x);
  u=a[4]; v=a[12]; a[4]=cadd(u,v); d=csub(u,v); a[12] = cmk(d.y, -d.x);
  u=a[5]; v=a[13]; a[5]=cadd(u,v); d=csub(u,v); a[13] = cmk(K16A*d.y - K16B*d.x, -(K16A*d.x + K16B*d.y));
  u=a[6]; v=a[14]; a[6]=cadd(u,v); d=csub(u,v); a[14] = cmk(C8*(d.y-d.x), -C8*(d.x+d.y));
  u=a[7]; v=a[15]; a[7]=cadd(u,v); d=csub(u,v); a[15] = cmk(K16B*d.y - K16A*d.x, -(K16A*d.y + K16B*d.x));
  fft8(a); fft8(a+8);
}

// ---------- fp32 butterfly set (k_czt + k_fft_u)
__device__ __forceinline__ void fft8s_bc(cf* a){
  cf u, v, d;
  u=a[0]; v=a[2]; a[0]=cfadd(u,v); a[2]=cfsub(u,v);
  u=a[1]; v=a[3]; a[1]=cfadd(u,v); d=cfsub(u,v); a[3]=cfmk(d.y, -d.x);
  u=a[4]; v=a[6]; a[4]=cfadd(u,v); a[6]=cfsub(u,v);
  u=a[5]; v=a[7]; a[5]=cfadd(u,v); d=cfsub(u,v); a[7]=cfmk(d.y, -d.x);
  u=a[0]; v=a[1]; a[0]=cfadd(u,v); a[1]=cfsub(u,v);
  u=a[2]; v=a[3]; a[2]=cfadd(u,v); a[3]=cfsub(u,v);
  u=a[4]; v=a[5]; a[4]=cfadd(u,v); a[5]=cfsub(u,v);
  u=a[6]; v=a[7]; a[6]=cfadd(u,v); a[7]=cfsub(u,v);
}
__device__ __forceinline__ void fft8s(cf* a){
  cf u, v, d;
  u=a[0]; v=a[4]; a[0]=cfadd(u,v); a[4]=cfsub(u,v);
  u=a[1]; v=a[5]; a[1]=cfadd(u,v); d=cfsub(u,v); a[5]=cfmk(C8f*(d.x+d.y), C8f*(d.y-d.x));
  u=a[2]; v=a[6]; a[2]=cfadd(u,v); d=cfsub(u,v); a[6]=cfmk(d.y, -d.x);
  u=a[3]; v=a[7]; a[3]=cfadd(u,v); d=cfsub(u,v); a[7]=cfmk(C8f*(d.y-d.x), -C8f*(d.x+d.y));
  fft8s_bc(a);
}
__device__ __forceinline__ void ifft8s(cf* a){
  cf u, v, t;
  u=a[0]; v=a[1]; a[0]=cfadd(u,v); a[1]=cfsub(u,v);
  u=a[2]; v=a[3]; a[2]=cfadd(u,v); a[3]=cfsub(u,v);
  u=a[4]; v=a[5]; a[4]=cfadd(u,v); a[5]=cfsub(u,v);
  u=a[6]; v=a[7]; a[6]=cfadd(u,v); a[7]=cfsub(u,v);
  u=a[0]; v=a[2]; a[0]=cfadd(u,v); a[2]=cfsub(u,v);
  u=a[1]; t=a[3]; v=cfmk(-t.y, t.x); a[1]=cfadd(u,v); a[3]=cfsub(u,v);
  u=a[4]; v=a[6]; a[4]=cfadd(u,v); a[6]=cfsub(u,v);
  u=a[5]; t=a[7]; v=cfmk(-t.y, t.x); a[5]=cfadd(u,v); a[7]=cfsub(u,v);
  u=a[0]; v=a[4]; a[0]=cfadd(u,v); a[4]=cfsub(u,v);
  u=a[1]; t=a[5]; v=cfmk(C8f*(t.x-t.y), C8f*(t.x+t.y)); a[1]=cfadd(u,v); a[5]=cfsub(u,v);
  u=a[2]; t=a[6]; v=cfmk(-t.y, t.x); a[2]=cfadd(u,v); a[6]=cfsub(u,v);
  u=a[3]; t=a[7]; v=cfmk(-C8f*(t.x+t.y), C8f*(t.x-t.y)); a[3]=cfadd(u,v); a[7]=cfsub(u,v);
}
__device__ __forceinline__ void fft4s(cf* a){
  cf u, v, d;
  u=a[0]; v=a[2]; a[0]=cfadd(u,v); a[2]=cfsub(u,v);
  u=a[1]; v=a[3]; a[1]=cfadd(u,v); d=cfsub(u,v); a[3]=cfmk(d.y, -d.x);
  u=a[0]; v=a[1]; a[0]=cfadd(u,v); a[1]=cfsub(u,v);
  u=a[2]; v=a[3]; a[2]=cfadd(u,v); a[3]=cfsub(u,v);
}
__device__ __forceinline__ void ffts16(cf* a){
  cf u, v, d;
  u=a[0]; v=a[8];  a[0]=cfadd(u,v); a[8] = cfsub(u,v);
  u=a[1]; v=a[9];  a[1]=cfadd(u,v); d=cfsub(u,v); a[9]  = cfmk(K16Af*d.x + K16Bf*d.y, K16Af*d.y - K16Bf*d.x);
  u=a[2]; v=a[10]; a[2]=cfadd(u,v); d=cfsub(u,v); a[10] = cfmk(C8f*(d.x+d.y), C8f*(d.y-d.x));
  u=a[3]; v=a[11]; a[3]=cfadd(u,v); d=cfsub(u,v); a[11] = cfmk(K16Bf*d.x + K16Af*d.y, K16Bf*d.y - K16Af*d.x);
  u=a[4]; v=a[12]; a[4]=cfadd(u,v); d=cfsub(u,v); a[12] = cfmk(d.y, -d.x);
  u=a[5]; v=a[13]; a[5]=cfadd(u,v); d=cfsub(u,v); a[13] = cfmk(K16Af*d.y - K16Bf*d.x, -(K16Af*d.x + K16Bf*d.y));
  u=a[6]; v=a[14]; a[6]=cfadd(u,v); d=cfsub(u,v); a[14] = cfmk(C8f*(d.y-d.x), -C8f*(d.x+d.y));
  u=a[7]; v=a[15]; a[7]=cfadd(u,v); d=cfsub(u,v); a[15] = cfmk(K16Bf*d.y - K16Af*d.x, -(K16Af*d.y + K16Bf*d.x));
  fft8s(a); fft8s(a+8);
}
__device__ __forceinline__ void ffts16h(cf* a){
  a[8]  = a[0];
  a[9]  = cfmk(K16Af*a[1].x + K16Bf*a[1].y, K16Af*a[1].y - K16Bf*a[1].x);
  a[10] = cfmk(C8f*(a[2].x+a[2].y), C8f*(a[2].y-a[2].x));
  a[11] = cfmk(K16Bf*a[3].x + K16Af*a[3].y, K16Bf*a[3].y - K16Af*a[3].x);
  a[12] = cfmk(a[4].y, -a[4].x);
  a[13] = cfmk(K16Af*a[5].y - K16Bf*a[5].x, -(K16Af*a[5].x + K16Bf*a[5].y));
  a[14] = cfmk(C8f*(a[6].y-a[6].x), -C8f*(a[6].x+a[6].y));
  a[15] = cfmk(K16Bf*a[7].y - K16Af*a[7].x, -(K16Af*a[7].y + K16Bf*a[7].x));
  fft8s(a); fft8s(a+8);
}
__device__ __forceinline__ void iffts16(cf* a){
  ifft8s(a); ifft8s(a+8);
  cf t, E;
  E=a[0]; t=a[8];                                                                   a[0]=cfadd(E,t); a[8] =cfsub(E,t);
  E=a[1]; t=cfmk(K16Af*a[9].x - K16Bf*a[9].y,  K16Af*a[9].y + K16Bf*a[9].x);        a[1]=cfadd(E,t); a[9] =cfsub(E,t);
  E=a[2]; t=cfmk(C8f*(a[10].x - a[10].y),      C8f*(a[10].x + a[10].y));            a[2]=cfadd(E,t); a[10]=cfsub(E,t);
  E=a[3]; t=cfmk(K16Bf*a[11].x - K16Af*a[11].y, K16Bf*a[11].y + K16Af*a[11].x);     a[3]=cfadd(E,t); a[11]=cfsub(E,t);
  E=a[4]; t=cfmk(-a[12].y, a[12].x);                                                a[4]=cfadd(E,t); a[12]=cfsub(E,t);
  E=a[5]; t=cfmk(-(K16Bf*a[13].x) - K16Af*a[13].y, K16Af*a[13].x - K16Bf*a[13].y);  a[5]=cfadd(E,t); a[13]=cfsub(E,t);
  E=a[6]; t=cfmk(-C8f*(a[14].x + a[14].y),     C8f*(a[14].x - a[14].y));            a[6]=cfadd(E,t); a[14]=cfsub(E,t);
  E=a[7]; t=cfmk(-(K16Af*a[15].x) - K16Bf*a[15].y, K16Bf*a[15].x - K16Af*a[15].y);  a[7]=cfadd(E,t); a[15]=cfsub(E,t);
}
__device__ __forceinline__ void iffts16h(cf* a){
  ifft8s(a); ifft8s(a+8);
  cf t;
  t=a[8];                                                                  a[0]=cfadd(a[0],t);
  t=cfmk(K16Af*a[9].x - K16Bf*a[9].y,  K16Af*a[9].y + K16Bf*a[9].x);       a[1]=cfadd(a[1],t);
  t=cfmk(C8f*(a[10].x - a[10].y),      C8f*(a[10].x + a[10].y));           a[2]=cfadd(a[2],t);
  t=cfmk(K16Bf*a[11].x - K16Af*a[11].y, K16Bf*a[11].y + K16Af*a[11].x);    a[3]=cfadd(a[3],t);
  t=cfmk(-a[12].y, a[12].x);                                               a[4]=cfadd(a[4],t);
  t=cfmk(-(K16Bf*a[13].x) - K16Af*a[13].y, K16Af*a[13].x - K16Bf*a[13].y); a[5]=cfadd(a[5],t);
  t=cfmk(-C8f*(a[14].x + a[14].y),     C8f*(a[14].x - a[14].y));           a[6]=cfadd(a[6],t);
  t=cfmk(-(K16Af*a[15].x) - K16Bf*a[15].y, K16Bf*a[15].x - K16Af*a[15].y); a[7]=cfadd(a[7],t);
}

// ---------- SO(3) helpers
__device__ __forceinline__ void mat_mul3(double* D, const double* A, const double* B){
  double r[9];
  #pragma unroll
  for (int i = 0; i < 3; i++)
    #pragma unroll
    for (int j = 0; j < 3; j++)
      r[i*3+j] = A[i*3]*B[j] + A[i*3+1]*B[3+j] + A[i*3+2]*B[6+j];
  #pragma unroll
  for (int k = 0; k < 9; k++) D[k] = r[k];
}
__device__ __forceinline__ void rod3(double* M, const double* a1, const double* a2,
                                     double z1, double z2){
  double G[9];
  #pragma unroll
  for (int k = 0; k < 9; k++) G[k] = a1[k]*z1 + a2[k]*z2;
  double wx = G[7], wy = G[2], wz = G[3];
  double th2 = wx*wx + wy*wy + wz*wz;
  double sa, cb;
  if (th2 < 1e-12){ sa = 1.0 - th2/6.0; cb = 0.5 - th2/24.0; }
  else { double th = sqrt(th2); sa = sin(th)/th; cb = (1.0 - cos(th))/th2; }
  double w[3] = {wx, wy, wz};
  #pragma unroll
  for (int i = 0; i < 3; i++)
    #pragma unroll
    for (int j = 0; j < 3; j++){
      double v = sa * G[i*3+j] + cb * (w[i]*w[j]);
      if (i == j) v += 1.0 - cb * th2;
      M[i*3+j] = v;
    }
}

// ---------- K_front: k_prep MERGED IN (R9 post-mortem: clean launch-count test,
// 5 stream ops -> 4 launches, no memset, no memory-pattern change).
// bid 0-63 = SO(3) scan (critical path, dispatches first); bid 64 = chat builder
// (fp64 twiddles computed inline — identical to dead tw[] table); bid 65 = tw32 +
// g2 tables; bid 66-321 = H spectra (filter NN built into padded LDS tile, Q inline).
__global__ __launch_bounds__(256) void k_front(
    const float* x, const float* A1f, const float* A2f,
    const float* fw1, const float* fb1, const float* fw2, const float* fb2,
    const float* gw1, const float* gb1, const float* gw2, const float* gb2,
    const float* pw1, const float* pb1, const float* pw2, const float* pb2,
    const float* qw1, const float* qb1, const float* qw2, const float* qb2,
    cf* HsQ, float* Asc, cf* chatp, cf* tw32, cpx* g2)
{
  __shared__ double smem[8192];   // 64 KB union
  int tid = threadIdx.x;
  int bid = blockIdx.x;
  if (bid < 64){
    int b = bid;
    double (*S)[9] = (double(*)[9])smem;
    int k = tid;
    double a1[9], a2[9];
    #pragma unroll
    for (int i = 0; i < 3; i++)
      #pragma unroll
      for (int j = 0; j < 3; j++){
        a1[i*3+j] = (double)A1f[i*3+j] - (double)A1f[j*3+i];
        a2[i*3+j] = (double)A2f[i*3+j] - (double)A2f[j*3+i];
      }
    const float* xb = x + (size_t)b * TN * 2;
    double C[9] = {1,0,0, 0,1,0, 0,0,1};
    for (int i = 0; i < 8; i++){
      int t = k * 8 + i;
      if (t >= 1){
        double M[9];
        rod3(M, a1, a2, (double)xb[2*t], (double)xb[2*t+1]);
        mat_mul3(C, C, M);
      }
    }
    #pragma unroll
    for (int q = 0; q < 9; q++) S[k][q] = C[q];
    __syncthreads();
    for (int ofs = 1; ofs < 256; ofs <<= 1){
      double Lm[9], Rm[9];
      bool act = (k >= ofs);
      if (act){
        #pragma unroll
        for (int q = 0; q < 9; q++){ Lm[q] = S[k-ofs][q]; Rm[q] = S[k][q]; }
      }
      __syncthreads();
      if (act){
        double P[9];
        mat_mul3(P, Lm, Rm);
        #pragma unroll
        for (int q = 0; q < 9; q++) S[k][q] = P[q];
      }
      __syncthreads();
    }
    double P[9];
    if (k == 0){
      P[0]=1; P[1]=0; P[2]=0; P[3]=0; P[4]=1; P[5]=0; P[6]=0; P[7]=0; P[8]=1;
    } else {
      #pragma unroll
      for (int q = 0; q < 9; q++) P[q] = S[k-1][q];
    }
    for (int i = 0; i < 8; i++){
      int t = k * 8 + i;
      if (t >= 1){
        double M[9];
        rod3(M, a1, a2, (double)xb[2*t], (double)xb[2*t+1]);
        mat_mul3(P, P, M);
      }
      #pragma unroll
      for (int q = 0; q < 9; q++)
        Asc[(((size_t)b * 9 + q) << 11) + t] = (float)P[q];
    }
  } else if (bid == 64){
    // ---- chat: radix-16^3 DIF of chirp (MUST match k_czt stage decomposition).
    // Built in fp64 (inline twiddles), stored fp32 as chatp[(digit16<<8)|group].
    cpx* buf = (cpx*)smem;
    const int R16[16] = {0,8,4,12,2,10,6,14,1,9,5,13,3,11,7,15};
    for (int mq = tid; mq < NF; mq += 256){
      long long mm = (mq <= 2048) ? mq : (NF - mq);
      long long qq = (mm * mm) % L2F;
      double s, c;
      sincos(-PI_D * (double)qq / (double)LF, &s, &c);
      buf[SW(mq)] = cmk(c, s);
    }
    __syncthreads();
    // T1: stride 256
    {
      cpx a[16];
      #pragma unroll
      for (int k = 0; k < 16; k++) a[k] = buf[SW(tid + (k << 8))];
      fft16(a);
      #pragma unroll
      for (int q = 0; q < 16; q++){
        int d = R16[q]; cpx v = a[q];
        if (d) v = cmul(v, twd64(tid * d));
        buf[SW(tid + (d << 8))] = v;
      }
    }
    __syncthreads();
    // T2: stride 16
    {
      int m2 = tid & 15, base2 = ((tid >> 4) << 8) + m2;
      cpx a[16];
      #pragma unroll
      for (int k = 0; k < 16; k++) a[k] = buf[SW(base2 + (k << 4))];
      fft16(a);
      #pragma unroll
      for (int q = 0; q < 16; q++){
        int d = R16[q]; cpx v = a[q];
        if (d) v = cmul(v, twd64((m2 * d) << 4));
        buf[SW(base2 + (d << 4))] = v;
      }
    }
    __syncthreads();
    // T3: stride 1, stream straight to chatp (fp32)
    {
      cpx a[16];
      #pragma unroll
      for (int k = 0; k < 16; k++) a[k] = buf[SW((tid << 4) + k)];
      fft16(a);
      #pragma unroll
      for (int q = 0; q < 16; q++)
        chatp[(R16[q] << 8) | tid] = c2s(a[q]);
    }
  } else if (bid == 65){
    // ---- tables: tw32 (fp32 twiddle, 16/thread) + g2 (fp64, 8/thread)
    for (int i = tid; i < NF; i += 256){
      double s, c;
      sincos(-2.0 * PI_D * (double)i / 4096.0, &s, &c);
      tw32[i] = cfmk((float)c, (float)s);
    }
    for (int gi = tid; gi < TN; gi += 256){
      long long i = gi;
      double s, c;
      long long b2 = (i * i) % L2F;
      long long a2 = ((2LL * TN - 2 + i) * (TN - 1)) % LF;
      long long comb2 = (2 * a2 + b2) % L2F;
      double phi = PI_D * (double)comb2 / (double)LF;
      double scale = 1.0 / ((double)LF * (double)LF) / (4096.0 * 4096.0);
      sincos(2.0 * phi, &s, &c);
      g2[gi] = cmk(c * scale, s * scale);
    }
  } else {
    int hb = bid - 66;                   // 0..255
    int f = hb >> 6;
    // LDS layout: arrF = padded float[2056] (8.2 KB), part = cpx[256] after it
    float* arrF = (float*)smem;
    cpx* part = (cpx*)(smem + 1032);
    // build this filter's 2048 NN values into LDS (fp32, 8 evals/thread).
    // Pad index m + m/256: chunk-strided reads land on distinct banks.
    const float *W1, *B1, *W2, *B2;
    if (f == 0){ W1=fw1; B1=fb1; W2=fw2; B2=fb2; }
    else if (f == 1){ W1=gw1; B1=gb1; W2=gw2; B2=gb2; }
    else if (f == 2){ W1=pw1; B1=pb1; W2=pw2; B2=pb2; }
    else { W1=qw1; B1=qb1; W2=qw2; B2=qb2; }
    for (int k = 0; k < 8; k++){
      int m = tid + (k << 8);
      int s = (f == 0 || f == 2) ? (TN - 1 - m) : m;
      float sv = (float)s;
      float z = B2[0];
      #pragma unroll
      for (int h = 0; h < 5; h++)
        z += W2[h] * tanhf(sv * W1[h] + B1[h]);
      arrF[m + (m >> 8)] = z * expf(-5.0f * sv);
    }
    __syncthreads();
    int jbase = (hb & 63) * 32;
    int chunk = tid & 7;
    int jl = tid >> 3;
    long long j = jbase + jl;
    long long jj = j + TN - 1;
    double s, c;
    sincos(-2.0 * PI_D * (double)jj / (double)LF, &s, &c);
    cpx W = cmk(c, s);
    long long m0 = (long long)chunk * 256;
    long long p0 = ((m0 + TN - 1) * jj) % LF;
    sincos(-2.0 * PI_D * (double)p0 / (double)LF, &s, &c);
    cpx ph = cmk(c, s);
    cpx acc = cmk(0.0, 0.0);
    for (int m = (int)m0; m < (int)m0 + 256; m++){
      double av = (double)arrF[m + (m >> 8)];
      acc.x += av * ph.x;
      acc.y += av * ph.y;
      ph = cmul(ph, W);
    }
    part[tid] = acc;
    __syncthreads();
    if (chunk == 0){
      cpx tot = cmk(0.0, 0.0);
      for (int q = 0; q < 8; q++) tot = cadd(tot, part[(jl << 3) + q]);
      // Q[j] inline (verbatim formula from the old k_prep)
      long long i = j;
      long long aq = ((2LL * TN - 2) * i) % LF;
      long long bq = (i * i) % L2F;
      long long comb = (2 * aq + bq) % L2F;
      sincos(PI_D * (double)comb / (double)LF, &s, &c);
      HsQ[f * TN + (int)j] = c2s(cmul(tot, cmk(c, s)));
    }
  }
}

// ---------- K3: 2048-pt FFT, real-pair packed — fp32. 256 threads, 16 KB LDS.
__global__ __launch_bounds__(256, 4) void k_fft_u(const float* Asc, const cf* tw32, cf* U){
  __shared__ cf buf[TN];                 // 16 KB
  int pos = threadIdx.x;                 // 0..255
  int b = blockIdx.x / 5, p = blockIdx.x % 5;
  int c0 = 2 * p;
  bool dual = (p < 4);
  const float* s0 = Asc + (((size_t)b * 9 + c0) << 11);
  const float* s1 = Asc + (((size_t)b * 9 + (dual ? c0 + 1 : c0)) << 11);
  const int R8[8] = {0,4,2,6,1,5,3,7};
  // C1: radix-8 stride 256, packed z = ch_a + i*ch_b staged directly from global
  {
    cf a[8];
    #pragma unroll
    for (int j = 0; j < 8; j++){
      int idx = pos + (j << 8);
      a[j] = cfmk(s0[idx], dual ? s1[idx] : 0.0f);
    }
    fft8s(a);
    #pragma unroll
    for (int q = 0; q < 8; q++){
      int k = R8[q]; cf v = a[q];
      if (k) v = cfmul(v, tw32[(pos * k) << 1]);
      buf[SW(pos + (k << 8))] = v;
    }
  }
  __syncthreads();
  // wave-local: 8 segments of 256; wave w owns segments 2w, 2w+1
  int l = pos & 63;
  int ll = l & 31;
  int segb = ((((pos >> 6) << 1) + (l >> 5)) << 8);
  // CA: stride 32
  {
    int base = segb + ll;
    cf a[8];
    #pragma unroll
    for (int j = 0; j < 8; j++) a[j] = buf[SW(base + (j << 5))];
    fft8s(a);
    #pragma unroll
    for (int q = 0; q < 8; q++){
      int k = R8[q]; cf v = a[q];
      if (k) v = cfmul(v, tw32[(ll * k) << 4]);
      buf[SW(base + (k << 5))] = v;
    }
  }
  wsync();
  // CB: stride 4
  {
    int base = segb + ((ll >> 2) << 5) + (ll & 3);
    cf a[8];
    #pragma unroll
    for (int j = 0; j < 8; j++) a[j] = buf[SW(base + (j << 2))];
    fft8s(a);
    #pragma unroll
    for (int q = 0; q < 8; q++){
      int k = R8[q]; cf v = a[q];
      if (k) v = cfmul(v, tw32[((ll & 3) * k) << 7]);
      buf[SW(base + (k << 2))] = v;
    }
  }
  wsync();
  // CC: radix-4, stride 1 (2 groups per lane)
  {
    const int R4[4] = {0,2,1,3};
    #pragma unroll
    for (int h = 0; h < 2; h++){
      int base = segb + (((ll << 1) + h) << 2);
      cf a4[4];
      #pragma unroll
      for (int j = 0; j < 4; j++) a4[j] = buf[SW(base + j)];
      fft4s(a4);
      #pragma unroll
      for (int q = 0; q < 4; q++) buf[SW(base + R4[q])] = a4[q];
    }
  }
  __syncthreads();
  // unscramble + Hermitian unpack -> U rows c0, c0+1 (natural order, coalesced)
  cf* dst0 = U + (((size_t)b * 9 + c0) << 11);
  cf* dst1 = U + (((size_t)b * 9 + c0 + 1) << 11);
  #pragma unroll
  for (int ii = 0; ii < 8; ii++){
    int f = pos + (ii << 8);
    int s  = ((f & 7) << 8) + (((f >> 3) & 7) << 5) + (((f >> 6) & 7) << 2) + (f >> 9);
    int m  = (TN - f) & (TN - 1);
    int sm = ((m & 7) << 8) + (((m >> 3) & 7) << 5) + (((m >> 6) & 7) << 2) + (m >> 9);
    cf Z = buf[SW(s)], Zm = buf[SW(sm)];
    dst0[f] = cfmk(0.5f * (Z.x + Zm.x), 0.5f * (Z.y - Zm.y));       // (Z + conj(Zm))/2
    if (dual)
      dst1[f] = cfmk(0.5f * (Z.y + Zm.y), 0.5f * (Zm.x - Z.x));     // (Z - conj(Zm))/(2i)
  }
}

// ---------- K4: CZT pair kernel — fp32 compute, pair-interleaved float4 LDS.
// Epilogue REVERTED to coalesced Rst write (R9 post-mortem: atomicAdd scatter
// to out[b][r][c] was stride-36B uncoalesced RMW -> WRITE_SIZE 9.2->73.7 MB,
// +38 us. k_out's LDS transpose is the right tool; keep it.)
__global__ __launch_bounds__(256, 2) void k_czt(const cf* U, const cf* HsQ, const cf* tw32,
                                                const cf* chatp, const cpx* g2, float* Rst){
  __shared__ float4 bufp[NF];            // 64 KB: {a.re, a.im, b.re, b.im} per position
  int gb = blockIdx.x;
  int pair = gb & 1;
  int bc = gb >> 1;
  int b = bc / 9, c = bc % 9;
  int ct = (c % 3) * 3 + (c / 3);        // inv(A) = A^T for SO(3)
  const cf* Us0 = U + ((size_t)b * 9 + ct) * TN;   // e=0 operand
  const cf* Us1 = U + ((size_t)b * 9 + c)  * TN;   // e=1 operand
  const cf* H0 = HsQ + ((size_t)(pair << 1) << 11);
  const cf* H1 = HsQ + ((size_t)((pair << 1) | 1) << 11);
  int t = threadIdx.x;                   // 0..255 (= group index in every stage)
  int m = t & 15;                        // T2 pos within its 256-block
  int base2 = ((t >> 4) << 8) + m;       // T2 base (wave-local)
  int base3 = t << 4;                    // T3 base (wave-local, 16 contiguous)
  const int R16[16] = {0,8,4,12,2,10,6,14,1,9,5,13,3,11,7,15};

  cf a[16], bb[16];
  // T1: radix-16 stride 256; staging fused, upper half (p>=2048) zero; both passes
  #pragma unroll
  for (int k = 0; k < 8; k++){
    a[k]  = cfmul(Us0[t + (k << 8)], H0[t + (k << 8)]);
    bb[k] = cfmul(Us1[t + (k << 8)], H1[t + (k << 8)]);
  }
  ffts16h(a); ffts16h(bb);
  #pragma unroll
  for (int q = 0; q < 16; q++){
    int d = R16[q];
    cf va = a[q], vb = bb[q];
    if (d){ cf tv = tw32[t * d]; va = cfmul(va, tv); vb = cfmul(vb, tv); }
    bufp[SWP(t + (d << 8))] = make_float4(va.x, va.y, vb.x, vb.y);
  }
  __syncthreads();
  // T2: radix-16 stride 16 (wave-local)
  #pragma unroll
  for (int k = 0; k < 16; k++){
    float4 p = bufp[SWP(base2 + (k << 4))];
    a[k]  = cfmk(p.x, p.y);
    bb[k] = cfmk(p.z, p.w);
  }
  ffts16(a); ffts16(bb);
  #pragma unroll
  for (int q = 0; q < 16; q++){
    int d = R16[q];
    cf va = a[q], vb = bb[q];
    if (d){ cf tv = tw32[(m * d) << 4]; va = cfmul(va, tv); vb = cfmul(vb, tv); }
    bufp[SWP(base2 + (d << 4))] = make_float4(va.x, va.y, vb.x, vb.y);
  }
  wsync();
  // T3 + chat + invT3 fused in registers (stride 1)
  #pragma unroll
  for (int k = 0; k < 16; k++){
    float4 p = bufp[SWP(base3 + k)];
    a[k]  = cfmk(p.x, p.y);
    bb[k] = cfmk(p.z, p.w);
  }
  ffts16(a); ffts16(bb);
  #pragma unroll
  for (int q = 0; q < 16; q++){
    cf ch = chatp[(R16[q] << 8) | t];
    a[q] = cfmul(a[q], ch);
    bb[q] = cfmul(bb[q], ch);
  }
  iffts16(a); iffts16(bb);
  #pragma unroll
  for (int k = 0; k < 16; k++)
    bufp[SWP(base3 + k)] = make_float4(a[k].x, a[k].y, bb[k].x, bb[k].y);
  wsync();
  // invT2 (wave-local)
  #pragma unroll
  for (int q = 0; q < 16; q++){
    int d = R16[q];
    float4 p = bufp[SWP(base2 + (d << 4))];
    cf va = cfmk(p.x, p.y), vb = cfmk(p.z, p.w);
    if (d){ cf tv = tw32[(m * d) << 4]; va = cfmulc(va, tv); vb = cfmulc(vb, tv); }
    a[q] = va; bb[q] = vb;
  }
  iffts16(a); iffts16(bb);
  #pragma unroll
  for (int k = 0; k < 16; k++)
    bufp[SWP(base2 + (k << 4))] = make_float4(a[k].x, a[k].y, bb[k].x, bb[k].y);
  __syncthreads();
  // invT1: outputs r = t + 256j, j<8 (r < 2048); pruned iffts16h; product (fp64) + g2 + store
  #pragma unroll
  for (int q = 0; q < 16; q++){
    int d = R16[q];
    float4 p = bufp[SWP(t + (d << 8))];
    cf va = cfmk(p.x, p.y), vb = cfmk(p.z, p.w);
    if (d){ cf tv = tw32[t * d]; va = cfmulc(va, tv); vb = cfmulc(vb, tv); }
    a[q] = va; bb[q] = vb;
  }
  iffts16h(a); iffts16h(bb);
  size_t rb = ((size_t)(pair * (NB * 9) + bc) << 11);
  #pragma unroll
  for (int j = 0; j < 8; j++){
    int r = t + (j << 8);
    double ax = (double)a[j].x, ay = (double)a[j].y;
    double bx = (double)bb[j].x, by = (double)bb[j].y;
    double prx = ax * bx - ay * by;
    double pry = ax * by + ay * bx;
    cpx g = g2[r];
    Rst[rb + r] = (float)(prx * g.x - pry * g.y);
  }
}

// ---------- K5: combine pair partials + transpose [b][c][r] -> out[b][r][c]
__global__ __launch_bounds__(256) void k_out(const float* Rst, float* out){
  __shared__ float ld[9][513];
  int b = blockIdx.x >> 2;
  int r0 = (blockIdx.x & 3) << 9;
  for (int idx = threadIdx.x; idx < 9 * 512; idx += 256){
    int cc = idx >> 9, r = idx & 511;
    size_t o0 = ((size_t)(b * 9 + cc) << 11) + r0 + r;
    ld[cc][r] = Rst[o0] + Rst[o0 + ((size_t)(NB * 9) << 11)];
  }
  __syncthreads();
  for (int idx = threadIdx.x; idx < 512 * 9; idx += 256){
    int r = idx / 9, cc = idx - 9 * r;
    out[((size_t)b * TN + r0 + r) * 9 + cc] = ld[cc][r];
  }
}

extern "C" void kernel_launch(void* const* d_in, const int* in_sizes, int n_in,
                              void* d_out, int out_size, void* d_ws, size_t ws_size,
                              hipStream_t stream){
  const float* x  = (const float*)d_in[0];
  const float* A1 = (const float*)d_in[1];
  const float* A2 = (const float*)d_in[2];
  const float* fpar[16];
  for (int i = 0; i < 16; i++) fpar[i] = (const float*)d_in[3 + i];
  float* out = (float*)d_out;

  // workspace carve (units: doubles; cf = 1 double-slot), total ~19 MB
  double* ws = (double*)d_ws;
  size_t o = 0;
  cf* HsQ      = (cf*)(ws + o);  o += 4 * TN;                    // 4 rows x TN, fp32
  cf* tw32     = (cf*)(ws + o);  o += NF;                        // fp32 (k_fft_u/k_czt)
  cf* chatp    = (cf*)(ws + o);  o += NF;                        // fp32 (k_czt)
  cpx* g2      = (cpx*)(ws + o); o += 2 * TN;
  // union region: Asc (fp32, 4.7 MB) then Rst (9.4 MB) — reserve the max (9.4 MB)
  double* uni  = ws + o;         o += (size_t)NB * TN * 9;
  float* Asc   = (float*)uni;    // NB*9*TN floats = 4.7 MB (dead after k_fft_u)
  float* Rst   = (float*)uni;    // 2*576*2048 floats = 9.4 MB exact fit
  cf* U        = (cf*)(ws + o);  o += (size_t)NB * 9 * TN;       // 9.4 MB (fp32)

  k_front<<<322, 256, 0, stream>>>(x, A1, A2,
                                   fpar[0], fpar[1], fpar[2], fpar[3],
                                   fpar[4], fpar[5], fpar[6], fpar[7],
                                   fpar[8], fpar[9], fpar[10], fpar[11],
                                   fpar[12], fpar[13], fpar[14], fpar[15],
                                   HsQ, Asc, chatp, tw32, g2);
  k_fft_u<<<NB * 5, 256, 0, stream>>>(Asc, tw32, U);
  k_czt<<<NB * 9 * 2, 256, 0, stream>>>(U, HsQ, tw32, chatp, g2, Rst);
  k_out<<<NB * 4, 256, 0, stream>>>(Rst, out);
}

// Round 11
// 188.131 us; speedup vs baseline: 1.3460x; 1.3460x over previous
//
#include <hip/hip_runtime.h>
#include <math.h>

#define TN 2048            // T
#define NF 4096            // Bluestein FFT length
#define NB 64              // batch
#define LF 6142LL          // L = 3T-2
#define L2F 12284LL        // 2L
#define PI_D 3.14159265358979323846264338327950288
#define C8 0.70710678118654752440084436210485
#define K16A 0.92387953251128675612818318939678828682   // cos(pi/8)
#define K16B 0.38268343236508977172845998403039886676   // sin(pi/8)
#define C8f   0.70710678118654752440f
#define K16Af 0.92387953251128675613f
#define K16Bf 0.38268343236508977173f

// R10 post-mortem: REVERT to the best-measured configuration (186.3 us).
// R8 (fp32 k_fft_u) was null; R9 (atomic epilogue) +30 us via uncoalesced RMW;
// R10 (k_prep merge) made k_front the pole (99.4 us, occ 4.9% serial tail).
// This source = the R6 submission verbatim: all validated wins, none of the
// regressions. k_czt: fused e-passes + ILP=2 + 8 waves/CU + SWP float4 LDS +
// fp32 registers (50.6 us measured, absmax bit-identical to fp64).

typedef double2 cpx;
typedef float2 cf;

__device__ __forceinline__ cpx cmk(double a, double b){ cpx r; r.x=a; r.y=b; return r; }
__device__ __forceinline__ cpx cadd(cpx a, cpx b){ return cmk(a.x+b.x, a.y+b.y); }
__device__ __forceinline__ cpx csub(cpx a, cpx b){ return cmk(a.x-b.x, a.y-b.y); }
__device__ __forceinline__ cpx cmul(cpx a, cpx b){ return cmk(a.x*b.x - a.y*b.y, a.x*b.y + a.y*b.x); }
__device__ __forceinline__ cpx cmulc(cpx a, cpx b){ return cmk(a.x*b.x + a.y*b.y, a.y*b.x - a.x*b.y); } // a*conj(b)
__device__ __forceinline__ cf c2s(cpx a){ cf r; r.x=(float)a.x; r.y=(float)a.y; return r; }

__device__ __forceinline__ cf cfmk(float a, float b){ cf r; r.x=a; r.y=b; return r; }
__device__ __forceinline__ cf cfadd(cf a, cf b){ return cfmk(a.x+b.x, a.y+b.y); }
__device__ __forceinline__ cf cfsub(cf a, cf b){ return cfmk(a.x-b.x, a.y-b.y); }
__device__ __forceinline__ cf cfmul(cf a, cf b){ return cfmk(a.x*b.x - a.y*b.y, a.x*b.y + a.y*b.x); }
__device__ __forceinline__ cf cfmulc(cf a, cf b){ return cfmk(a.x*b.x + a.y*b.y, a.y*b.x - a.x*b.y); }

// LDS swizzle, element granularity — k_front (cpx) / k_fft_u (cpx)
__device__ __forceinline__ int SW(int i){ return i ^ ((i >> 3) & 7) ^ ((i >> 6) & 7); }
// LDS swizzle, pair (16 B float4) granularity — k_czt. Involution; bank-ideal
// for stride 256/16/1 patterns (verified R7: conflicts 1.18M -> 36.9K).
__device__ __forceinline__ int SWP(int i){ return i ^ ((i >> 4) & 15) ^ ((i >> 8) & 15); }

// wave-local sync: fences compiler + drains lgkmcnt; no cross-wave lock-step
__device__ __forceinline__ void wsync(){
  __builtin_amdgcn_wave_barrier();
  asm volatile("s_waitcnt lgkmcnt(0)" ::: "memory");
  __builtin_amdgcn_wave_barrier();
}

// ---------- fp64 8-point register FFT (DIF; reg q holds freq R8[q]={0,4,2,6,1,5,3,7})
__device__ __forceinline__ void fft8_bc(cpx* a){
  cpx u, v, d;
  u=a[0]; v=a[2]; a[0]=cadd(u,v); a[2]=csub(u,v);
  u=a[1]; v=a[3]; a[1]=cadd(u,v); d=csub(u,v); a[3]=cmk(d.y, -d.x);
  u=a[4]; v=a[6]; a[4]=cadd(u,v); a[6]=csub(u,v);
  u=a[5]; v=a[7]; a[5]=cadd(u,v); d=csub(u,v); a[7]=cmk(d.y, -d.x);
  u=a[0]; v=a[1]; a[0]=cadd(u,v); a[1]=csub(u,v);
  u=a[2]; v=a[3]; a[2]=cadd(u,v); a[3]=csub(u,v);
  u=a[4]; v=a[5]; a[4]=cadd(u,v); a[5]=csub(u,v);
  u=a[6]; v=a[7]; a[6]=cadd(u,v); a[7]=csub(u,v);
}
__device__ __forceinline__ void fft8(cpx* a){
  cpx u, v, d;
  u=a[0]; v=a[4]; a[0]=cadd(u,v); a[4]=csub(u,v);
  u=a[1]; v=a[5]; a[1]=cadd(u,v); d=csub(u,v); a[5]=cmk(C8*(d.x+d.y), C8*(d.y-d.x));
  u=a[2]; v=a[6]; a[2]=cadd(u,v); d=csub(u,v); a[6]=cmk(d.y, -d.x);
  u=a[3]; v=a[7]; a[3]=cadd(u,v); d=csub(u,v); a[7]=cmk(C8*(d.y-d.x), -C8*(d.x+d.y));
  fft8_bc(a);
}
// ---------- fp64 16-point (k_front chat builder): W16 level + two fft8.
// Output reg q holds freq R16[q] = bitrev4(q).
__device__ __forceinline__ void fft16(cpx* a){
  cpx u, v, d;
  u=a[0]; v=a[8];  a[0]=cadd(u,v); a[8] = csub(u,v);
  u=a[1]; v=a[9];  a[1]=cadd(u,v); d=csub(u,v); a[9]  = cmk(K16A*d.x + K16B*d.y, K16A*d.y - K16B*d.x);
  u=a[2]; v=a[10]; a[2]=cadd(u,v); d=csub(u,v); a[10] = cmk(C8*(d.x+d.y), C8*(d.y-d.x));
  u=a[3]; v=a[11]; a[3]=cadd(u,v); d=csub(u,v); a[11] = cmk(K16B*d.x + K16A*d.y, K16B*d.y - K16A*d.x);
  u=a[4]; v=a[12]; a[4]=cadd(u,v); d=csub(u,v); a[12] = cmk(d.y, -d.x);
  u=a[5]; v=a[13]; a[5]=cadd(u,v); d=csub(u,v); a[13] = cmk(K16A*d.y - K16B*d.x, -(K16A*d.x + K16B*d.y));
  u=a[6]; v=a[14]; a[6]=cadd(u,v); d=csub(u,v); a[14] = cmk(C8*(d.y-d.x), -C8*(d.x+d.y));
  u=a[7]; v=a[15]; a[7]=cadd(u,v); d=csub(u,v); a[15] = cmk(K16B*d.y - K16A*d.x, -(K16A*d.y + K16B*d.x));
  fft8(a); fft8(a+8);
}
// fp64 4-point DIF (k_fft_u); reg q holds freq R4[q] = {0,2,1,3}
__device__ __forceinline__ void fft4(cpx* a){
  cpx u, v, d;
  u=a[0]; v=a[2]; a[0]=cadd(u,v); a[2]=csub(u,v);
  u=a[1]; v=a[3]; a[1]=cadd(u,v); d=csub(u,v); a[3]=cmk(d.y, -d.x);
  u=a[0]; v=a[1]; a[0]=cadd(u,v); a[1]=csub(u,v);
  u=a[2]; v=a[3]; a[2]=cadd(u,v); a[3]=csub(u,v);
}

// ---------- fp32 butterfly set (k_czt only)
__device__ __forceinline__ void fft8s_bc(cf* a){
  cf u, v, d;
  u=a[0]; v=a[2]; a[0]=cfadd(u,v); a[2]=cfsub(u,v);
  u=a[1]; v=a[3]; a[1]=cfadd(u,v); d=cfsub(u,v); a[3]=cfmk(d.y, -d.x);
  u=a[4]; v=a[6]; a[4]=cfadd(u,v); a[6]=cfsub(u,v);
  u=a[5]; v=a[7]; a[5]=cfadd(u,v); d=cfsub(u,v); a[7]=cfmk(d.y, -d.x);
  u=a[0]; v=a[1]; a[0]=cfadd(u,v); a[1]=cfsub(u,v);
  u=a[2]; v=a[3]; a[2]=cfadd(u,v); a[3]=cfsub(u,v);
  u=a[4]; v=a[5]; a[4]=cfadd(u,v); a[5]=cfsub(u,v);
  u=a[6]; v=a[7]; a[6]=cfadd(u,v); a[7]=cfsub(u,v);
}
__device__ __forceinline__ void fft8s(cf* a){
  cf u, v, d;
  u=a[0]; v=a[4]; a[0]=cfadd(u,v); a[4]=cfsub(u,v);
  u=a[1]; v=a[5]; a[1]=cfadd(u,v); d=cfsub(u,v); a[5]=cfmk(C8f*(d.x+d.y), C8f*(d.y-d.x));
  u=a[2]; v=a[6]; a[2]=cfadd(u,v); d=cfsub(u,v); a[6]=cfmk(d.y, -d.x);
  u=a[3]; v=a[7]; a[3]=cfadd(u,v); d=cfsub(u,v); a[7]=cfmk(C8f*(d.y-d.x), -C8f*(d.x+d.y));
  fft8s_bc(a);
}
__device__ __forceinline__ void ifft8s(cf* a){
  cf u, v, t;
  u=a[0]; v=a[1]; a[0]=cfadd(u,v); a[1]=cfsub(u,v);
  u=a[2]; v=a[3]; a[2]=cfadd(u,v); a[3]=cfsub(u,v);
  u=a[4]; v=a[5]; a[4]=cfadd(u,v); a[5]=cfsub(u,v);
  u=a[6]; v=a[7]; a[6]=cfadd(u,v); a[7]=cfsub(u,v);
  u=a[0]; v=a[2]; a[0]=cfadd(u,v); a[2]=cfsub(u,v);
  u=a[1]; t=a[3]; v=cfmk(-t.y, t.x); a[1]=cfadd(u,v); a[3]=cfsub(u,v);
  u=a[4]; v=a[6]; a[4]=cfadd(u,v); a[6]=cfsub(u,v);
  u=a[5]; t=a[7]; v=cfmk(-t.y, t.x); a[5]=cfadd(u,v); a[7]=cfsub(u,v);
  u=a[0]; v=a[4]; a[0]=cfadd(u,v); a[4]=cfsub(u,v);
  u=a[1]; t=a[5]; v=cfmk(C8f*(t.x-t.y), C8f*(t.x+t.y)); a[1]=cfadd(u,v); a[5]=cfsub(u,v);
  u=a[2]; t=a[6]; v=cfmk(-t.y, t.x); a[2]=cfadd(u,v); a[6]=cfsub(u,v);
  u=a[3]; t=a[7]; v=cfmk(-C8f*(t.x+t.y), C8f*(t.x-t.y)); a[3]=cfadd(u,v); a[7]=cfsub(u,v);
}
__device__ __forceinline__ void ffts16(cf* a){
  cf u, v, d;
  u=a[0]; v=a[8];  a[0]=cfadd(u,v); a[8] = cfsub(u,v);
  u=a[1]; v=a[9];  a[1]=cfadd(u,v); d=cfsub(u,v); a[9]  = cfmk(K16Af*d.x + K16Bf*d.y, K16Af*d.y - K16Bf*d.x);
  u=a[2]; v=a[10]; a[2]=cfadd(u,v); d=cfsub(u,v); a[10] = cfmk(C8f*(d.x+d.y), C8f*(d.y-d.x));
  u=a[3]; v=a[11]; a[3]=cfadd(u,v); d=cfsub(u,v); a[11] = cfmk(K16Bf*d.x + K16Af*d.y, K16Bf*d.y - K16Af*d.x);
  u=a[4]; v=a[12]; a[4]=cfadd(u,v); d=cfsub(u,v); a[12] = cfmk(d.y, -d.x);
  u=a[5]; v=a[13]; a[5]=cfadd(u,v); d=cfsub(u,v); a[13] = cfmk(K16Af*d.y - K16Bf*d.x, -(K16Af*d.x + K16Bf*d.y));
  u=a[6]; v=a[14]; a[6]=cfadd(u,v); d=cfsub(u,v); a[14] = cfmk(C8f*(d.y-d.x), -C8f*(d.x+d.y));
  u=a[7]; v=a[15]; a[7]=cfadd(u,v); d=cfsub(u,v); a[15] = cfmk(K16Bf*d.y - K16Af*d.x, -(K16Af*d.y + K16Bf*d.x));
  fft8s(a); fft8s(a+8);
}
__device__ __forceinline__ void ffts16h(cf* a){
  a[8]  = a[0];
  a[9]  = cfmk(K16Af*a[1].x + K16Bf*a[1].y, K16Af*a[1].y - K16Bf*a[1].x);
  a[10] = cfmk(C8f*(a[2].x+a[2].y), C8f*(a[2].y-a[2].x));
  a[11] = cfmk(K16Bf*a[3].x + K16Af*a[3].y, K16Bf*a[3].y - K16Af*a[3].x);
  a[12] = cfmk(a[4].y, -a[4].x);
  a[13] = cfmk(K16Af*a[5].y - K16Bf*a[5].x, -(K16Af*a[5].x + K16Bf*a[5].y));
  a[14] = cfmk(C8f*(a[6].y-a[6].x), -C8f*(a[6].x+a[6].y));
  a[15] = cfmk(K16Bf*a[7].y - K16Af*a[7].x, -(K16Af*a[7].y + K16Bf*a[7].x));
  fft8s(a); fft8s(a+8);
}
__device__ __forceinline__ void iffts16(cf* a){
  ifft8s(a); ifft8s(a+8);
  cf t, E;
  E=a[0]; t=a[8];                                                                   a[0]=cfadd(E,t); a[8] =cfsub(E,t);
  E=a[1]; t=cfmk(K16Af*a[9].x - K16Bf*a[9].y,  K16Af*a[9].y + K16Bf*a[9].x);        a[1]=cfadd(E,t); a[9] =cfsub(E,t);
  E=a[2]; t=cfmk(C8f*(a[10].x - a[10].y),      C8f*(a[10].x + a[10].y));            a[2]=cfadd(E,t); a[10]=cfsub(E,t);
  E=a[3]; t=cfmk(K16Bf*a[11].x - K16Af*a[11].y, K16Bf*a[11].y + K16Af*a[11].x);     a[3]=cfadd(E,t); a[11]=cfsub(E,t);
  E=a[4]; t=cfmk(-a[12].y, a[12].x);                                                a[4]=cfadd(E,t); a[12]=cfsub(E,t);
  E=a[5]; t=cfmk(-(K16Bf*a[13].x) - K16Af*a[13].y, K16Af*a[13].x - K16Bf*a[13].y);  a[5]=cfadd(E,t); a[13]=cfsub(E,t);
  E=a[6]; t=cfmk(-C8f*(a[14].x + a[14].y),     C8f*(a[14].x - a[14].y));            a[6]=cfadd(E,t); a[14]=cfsub(E,t);
  E=a[7]; t=cfmk(-(K16Af*a[15].x) - K16Bf*a[15].y, K16Bf*a[15].x - K16Af*a[15].y);  a[7]=cfadd(E,t); a[15]=cfsub(E,t);
}
__device__ __forceinline__ void iffts16h(cf* a){
  ifft8s(a); ifft8s(a+8);
  cf t;
  t=a[8];                                                                  a[0]=cfadd(a[0],t);
  t=cfmk(K16Af*a[9].x - K16Bf*a[9].y,  K16Af*a[9].y + K16Bf*a[9].x);       a[1]=cfadd(a[1],t);
  t=cfmk(C8f*(a[10].x - a[10].y),      C8f*(a[10].x + a[10].y));           a[2]=cfadd(a[2],t);
  t=cfmk(K16Bf*a[11].x - K16Af*a[11].y, K16Bf*a[11].y + K16Af*a[11].x);    a[3]=cfadd(a[3],t);
  t=cfmk(-a[12].y, a[12].x);                                               a[4]=cfadd(a[4],t);
  t=cfmk(-(K16Bf*a[13].x) - K16Af*a[13].y, K16Af*a[13].x - K16Bf*a[13].y); a[5]=cfadd(a[5],t);
  t=cfmk(-C8f*(a[14].x + a[14].y),     C8f*(a[14].x - a[14].y));           a[6]=cfadd(a[6],t);
  t=cfmk(-(K16Af*a[15].x) - K16Bf*a[15].y, K16Bf*a[15].x - K16Af*a[15].y); a[7]=cfadd(a[7],t);
}

// ---------- K1: filters + tables (adds fp32 twiddle copy for k_czt)
__global__ __launch_bounds__(256) void k_prep(
    const float* fw1, const float* fb1, const float* fw2, const float* fb2,
    const float* gw1, const float* gb1, const float* gw2, const float* gb2,
    const float* pw1, const float* pb1, const float* pw2, const float* pb2,
    const float* qw1, const float* qb1, const float* qw2, const float* qb2,
    double* arr, cpx* tw, cf* tw32, cpx* Q, cpx* g2)
{
  int gid = blockIdx.x * 256 + threadIdx.x;   // < 8192
  if (gid < 4096){
    double s, c;
    sincos(-2.0 * PI_D * (double)gid / 4096.0, &s, &c);
    tw[gid] = cmk(c, s);
    tw32[gid] = cfmk((float)c, (float)s);
  }
  if (gid < 2048){
    long long i = gid;
    double s, c;
    long long a = ((2LL * TN - 2) * i) % LF;
    long long b = (i * i) % L2F;
    long long comb = (2 * a + b) % L2F;
    sincos(PI_D * (double)comb / (double)LF, &s, &c);
    Q[gid] = cmk(c, s);
    long long a2 = ((2LL * TN - 2 + i) * (TN - 1)) % LF;
    long long comb2 = (2 * a2 + b) % L2F;
    double phi = PI_D * (double)comb2 / (double)LF;
    double scale = 1.0 / ((double)LF * (double)LF) / (4096.0 * 4096.0);
    sincos(2.0 * phi, &s, &c);
    g2[gid] = cmk(c * scale, s * scale);
  }
  int fid = gid >> 11;
  int m = gid & (TN - 1);
  const float *W1, *B1, *W2, *B2;
  if (fid == 0){ W1=fw1; B1=fb1; W2=fw2; B2=fb2; }
  else if (fid == 1){ W1=gw1; B1=gb1; W2=gw2; B2=gb2; }
  else if (fid == 2){ W1=pw1; B1=pb1; W2=pw2; B2=pb2; }
  else { W1=qw1; B1=qb1; W2=qw2; B2=qb2; }
  int s = (fid == 0 || fid == 2) ? (TN - 1 - m) : m;
  double sv = (double)s;
  double z = (double)B2[0];
  #pragma unroll
  for (int h = 0; h < 5; h++)
    z += (double)W2[h] * tanh(sv * (double)W1[h] + (double)B1[h]);
  arr[fid * TN + m] = z * exp(-5.0 * sv);
}

// ---------- SO(3) helpers
__device__ __forceinline__ void mat_mul3(double* D, const double* A, const double* B){
  double r[9];
  #pragma unroll
  for (int i = 0; i < 3; i++)
    #pragma unroll
    for (int j = 0; j < 3; j++)
      r[i*3+j] = A[i*3]*B[j] + A[i*3+1]*B[3+j] + A[i*3+2]*B[6+j];
  #pragma unroll
  for (int k = 0; k < 9; k++) D[k] = r[k];
}
__device__ __forceinline__ void rod3(double* M, const double* a1, const double* a2,
                                     double z1, double z2){
  double G[9];
  #pragma unroll
  for (int k = 0; k < 9; k++) G[k] = a1[k]*z1 + a2[k]*z2;
  double wx = G[7], wy = G[2], wz = G[3];
  double th2 = wx*wx + wy*wy + wz*wz;
  double sa, cb;
  if (th2 < 1e-12){ sa = 1.0 - th2/6.0; cb = 0.5 - th2/24.0; }
  else { double th = sqrt(th2); sa = sin(th)/th; cb = (1.0 - cos(th))/th2; }
  double w[3] = {wx, wy, wz};
  #pragma unroll
  for (int i = 0; i < 3; i++)
    #pragma unroll
    for (int j = 0; j < 3; j++){
      double v = sa * G[i*3+j] + cb * (w[i]*w[j]);
      if (i == j) v += 1.0 - cb * th2;
      M[i*3+j] = v;
    }
}

// ---------- K2 merged: blocks 0-255 = H spectra (xQ folded), 256-319 = SO(3) scan, 320 = chat
__global__ __launch_bounds__(256) void k_front(
    const float* x, const float* A1f, const float* A2f,
    const double* arr, const cpx* Q, const cpx* tw,
    cf* HsQ, double* Asc, cf* chatp)
{
  __shared__ double smem[8192];   // 64 KB union
  int tid = threadIdx.x;
  int bid = blockIdx.x;
  if (bid < 256){
    cpx* part = (cpx*)smem;
    int f = bid >> 6;
    int jbase = (bid & 63) * 32;
    int chunk = tid & 7;
    int jl = tid >> 3;
    long long j = jbase + jl;
    long long jj = j + TN - 1;
    double s, c;
    sincos(-2.0 * PI_D * (double)jj / (double)LF, &s, &c);
    cpx W = cmk(c, s);
    long long m0 = (long long)chunk * 256;
    long long p0 = ((m0 + TN - 1) * jj) % LF;
    sincos(-2.0 * PI_D * (double)p0 / (double)LF, &s, &c);
    cpx ph = cmk(c, s);
    const double* a = arr + f * TN;
    cpx acc = cmk(0.0, 0.0);
    for (int m = (int)m0; m < (int)m0 + 256; m++){
      double av = a[m];
      acc.x += av * ph.x;
      acc.y += av * ph.y;
      ph = cmul(ph, W);
    }
    part[tid] = acc;
    __syncthreads();
    if (chunk == 0){
      cpx tot = cmk(0.0, 0.0);
      for (int q = 0; q < 8; q++) tot = cadd(tot, part[(jl << 3) + q]);
      HsQ[f * TN + (int)j] = c2s(cmul(tot, Q[j]));
    }
  } else if (bid < 320){
    int b = bid - 256;
    double (*S)[9] = (double(*)[9])smem;
    int k = tid;
    double a1[9], a2[9];
    #pragma unroll
    for (int i = 0; i < 3; i++)
      #pragma unroll
      for (int j = 0; j < 3; j++){
        a1[i*3+j] = (double)A1f[i*3+j] - (double)A1f[j*3+i];
        a2[i*3+j] = (double)A2f[i*3+j] - (double)A2f[j*3+i];
      }
    const float* xb = x + (size_t)b * TN * 2;
    double C[9] = {1,0,0, 0,1,0, 0,0,1};
    for (int i = 0; i < 8; i++){
      int t = k * 8 + i;
      if (t >= 1){
        double M[9];
        rod3(M, a1, a2, (double)xb[2*t], (double)xb[2*t+1]);
        mat_mul3(C, C, M);
      }
    }
    #pragma unroll
    for (int q = 0; q < 9; q++) S[k][q] = C[q];
    __syncthreads();
    for (int ofs = 1; ofs < 256; ofs <<= 1){
      double Lm[9], Rm[9];
      bool act = (k >= ofs);
      if (act){
        #pragma unroll
        for (int q = 0; q < 9; q++){ Lm[q] = S[k-ofs][q]; Rm[q] = S[k][q]; }
      }
      __syncthreads();
      if (act){
        double P[9];
        mat_mul3(P, Lm, Rm);
        #pragma unroll
        for (int q = 0; q < 9; q++) S[k][q] = P[q];
      }
      __syncthreads();
    }
    double P[9];
    if (k == 0){
      P[0]=1; P[1]=0; P[2]=0; P[3]=0; P[4]=1; P[5]=0; P[6]=0; P[7]=0; P[8]=1;
    } else {
      #pragma unroll
      for (int q = 0; q < 9; q++) P[q] = S[k-1][q];
    }
    for (int i = 0; i < 8; i++){
      int t = k * 8 + i;
      if (t >= 1){
        double M[9];
        rod3(M, a1, a2, (double)xb[2*t], (double)xb[2*t+1]);
        mat_mul3(P, P, M);
      }
      #pragma unroll
      for (int q = 0; q < 9; q++)
        Asc[(((size_t)b * 9 + q) << 11) + t] = P[q];
    }
  } else {
    // ---- chat: radix-16^3 DIF of chirp (MUST match k_czt stage decomposition).
    // Built in fp64, stored fp32 as chatp[(digit16<<8) | group].
    cpx* buf = (cpx*)smem;
    const int R16[16] = {0,8,4,12,2,10,6,14,1,9,5,13,3,11,7,15};
    for (int mq = tid; mq < NF; mq += 256){
      long long mm = (mq <= 2048) ? mq : (NF - mq);
      long long qq = (mm * mm) % L2F;
      double s, c;
      sincos(-PI_D * (double)qq / (double)LF, &s, &c);
      buf[SW(mq)] = cmk(c, s);
    }
    __syncthreads();
    // T1: stride 256
    {
      cpx a[16];
      #pragma unroll
      for (int k = 0; k < 16; k++) a[k] = buf[SW(tid + (k << 8))];
      fft16(a);
      #pragma unroll
      for (int q = 0; q < 16; q++){
        int d = R16[q]; cpx v = a[q];
        if (d) v = cmul(v, tw[tid * d]);
        buf[SW(tid + (d << 8))] = v;
      }
    }
    __syncthreads();
    // T2: stride 16
    {
      int m2 = tid & 15, base2 = ((tid >> 4) << 8) + m2;
      cpx a[16];
      #pragma unroll
      for (int k = 0; k < 16; k++) a[k] = buf[SW(base2 + (k << 4))];
      fft16(a);
      #pragma unroll
      for (int q = 0; q < 16; q++){
        int d = R16[q]; cpx v = a[q];
        if (d) v = cmul(v, tw[(m2 * d) << 4]);
        buf[SW(base2 + (d << 4))] = v;
      }
    }
    __syncthreads();
    // T3: stride 1, stream straight to chatp (fp32)
    {
      cpx a[16];
      #pragma unroll
      for (int k = 0; k < 16; k++) a[k] = buf[SW((tid << 4) + k)];
      fft16(a);
      #pragma unroll
      for (int q = 0; q < 16; q++)
        chatp[(R16[q] << 8) | tid] = c2s(a[q]);
    }
  }
}

// ---------- K3: 2048-pt FFT, real-pair packed; fp64 compute, fp32 U output
// (halves write traffic; k_czt consumes fp32). 256 threads, 32 KB LDS.
__global__ __launch_bounds__(256, 4) void k_fft_u(const double* Asc, const cpx* tw, cf* U){
  __shared__ cpx buf[TN];
  int pos = threadIdx.x;                 // 0..255
  int b = blockIdx.x / 5, p = blockIdx.x % 5;
  int c0 = 2 * p;
  bool dual = (p < 4);
  const double* s0 = Asc + (((size_t)b * 9 + c0) << 11);
  const double* s1 = Asc + (((size_t)b * 9 + (dual ? c0 + 1 : c0)) << 11);
  const int R8[8] = {0,4,2,6,1,5,3,7};
  // C1: radix-8 stride 256, packed z = ch_a + i*ch_b staged directly from global
  {
    cpx a[8];
    #pragma unroll
    for (int j = 0; j < 8; j++){
      int idx = pos + (j << 8);
      a[j] = cmk(s0[idx], dual ? s1[idx] : 0.0);
    }
    fft8(a);
    #pragma unroll
    for (int q = 0; q < 8; q++){
      int k = R8[q]; cpx v = a[q];
      if (k) v = cmul(v, tw[(pos * k) << 1]);
      buf[SW(pos + (k << 8))] = v;
    }
  }
  __syncthreads();
  // wave-local: 8 segments of 256; wave w owns segments 2w, 2w+1
  int l = pos & 63;
  int ll = l & 31;
  int segb = ((((pos >> 6) << 1) + (l >> 5)) << 8);
  // CA: stride 32
  {
    int base = segb + ll;
    cpx a[8];
    #pragma unroll
    for (int j = 0; j < 8; j++) a[j] = buf[SW(base + (j << 5))];
    fft8(a);
    #pragma unroll
    for (int q = 0; q < 8; q++){
      int k = R8[q]; cpx v = a[q];
      if (k) v = cmul(v, tw[(ll * k) << 4]);
      buf[SW(base + (k << 5))] = v;
    }
  }
  wsync();
  // CB: stride 4
  {
    int base = segb + ((ll >> 2) << 5) + (ll & 3);
    cpx a[8];
    #pragma unroll
    for (int j = 0; j < 8; j++) a[j] = buf[SW(base + (j << 2))];
    fft8(a);
    #pragma unroll
    for (int q = 0; q < 8; q++){
      int k = R8[q]; cpx v = a[q];
      if (k) v = cmul(v, tw[((ll & 3) * k) << 7]);
      buf[SW(base + (k << 2))] = v;
    }
  }
  wsync();
  // CC: radix-4, stride 1 (2 groups per lane)
  {
    const int R4[4] = {0,2,1,3};
    #pragma unroll
    for (int h = 0; h < 2; h++){
      int base = segb + (((ll << 1) + h) << 2);
      cpx a4[4];
      #pragma unroll
      for (int j = 0; j < 4; j++) a4[j] = buf[SW(base + j)];
      fft4(a4);
      #pragma unroll
      for (int q = 0; q < 4; q++) buf[SW(base + R4[q])] = a4[q];
    }
  }
  __syncthreads();
  // unscramble + Hermitian unpack -> U rows c0, c0+1 (natural order, coalesced, fp32)
  cf* dst0 = U + (((size_t)b * 9 + c0) << 11);
  cf* dst1 = U + (((size_t)b * 9 + c0 + 1) << 11);
  #pragma unroll
  for (int ii = 0; ii < 8; ii++){
    int f = pos + (ii << 8);
    int s  = ((f & 7) << 8) + (((f >> 3) & 7) << 5) + (((f >> 6) & 7) << 2) + (f >> 9);
    int m  = (TN - f) & (TN - 1);
    int sm = ((m & 7) << 8) + (((m >> 3) & 7) << 5) + (((m >> 6) & 7) << 2) + (m >> 9);
    cpx Z = buf[SW(s)], Zm = buf[SW(sm)];
    dst0[f] = c2s(cmk(0.5 * (Z.x + Zm.x), 0.5 * (Z.y - Zm.y)));     // (Z + conj(Zm))/2
    if (dual)
      dst1[f] = c2s(cmk(0.5 * (Z.y + Zm.y), 0.5 * (Zm.x - Z.x)));   // (Z - conj(Zm))/(2i)
  }
}

// ---------- K4: CZT pair kernel — FULL fp32 compute, pair-interleaved float4 LDS.
// (R7-measured: 50.6 us, conflicts 36.9K, absmax unchanged vs fp64.)
__global__ __launch_bounds__(256, 2) void k_czt(const cf* U, const cf* HsQ, const cf* tw32,
                                                const cf* chatp, const cpx* g2, float* Rst){
  __shared__ float4 bufp[NF];            // 64 KB: {a.re, a.im, b.re, b.im} per position
  int gb = blockIdx.x;
  int pair = gb & 1;
  int bc = gb >> 1;
  int b = bc / 9, c = bc % 9;
  int ct = (c % 3) * 3 + (c / 3);        // inv(A) = A^T for SO(3)
  const cf* Us0 = U + ((size_t)b * 9 + ct) * TN;   // e=0 operand
  const cf* Us1 = U + ((size_t)b * 9 + c)  * TN;   // e=1 operand
  const cf* H0 = HsQ + ((size_t)(pair << 1) << 11);
  const cf* H1 = HsQ + ((size_t)((pair << 1) | 1) << 11);
  int t = threadIdx.x;                   // 0..255 (= group index in every stage)
  int m = t & 15;                        // T2 pos within its 256-block
  int base2 = ((t >> 4) << 8) + m;       // T2 base (wave-local)
  int base3 = t << 4;                    // T3 base (wave-local, 16 contiguous)
  const int R16[16] = {0,8,4,12,2,10,6,14,1,9,5,13,3,11,7,15};

  cf a[16], bb[16];
  // T1: radix-16 stride 256; staging fused, upper half (p>=2048) zero; both passes
  #pragma unroll
  for (int k = 0; k < 8; k++){
    a[k]  = cfmul(Us0[t + (k << 8)], H0[t + (k << 8)]);
    bb[k] = cfmul(Us1[t + (k << 8)], H1[t + (k << 8)]);
  }
  ffts16h(a); ffts16h(bb);
  #pragma unroll
  for (int q = 0; q < 16; q++){
    int d = R16[q];
    cf va = a[q], vb = bb[q];
    if (d){ cf tv = tw32[t * d]; va = cfmul(va, tv); vb = cfmul(vb, tv); }
    bufp[SWP(t + (d << 8))] = make_float4(va.x, va.y, vb.x, vb.y);
  }
  __syncthreads();
  // T2: radix-16 stride 16 (wave-local)
  #pragma unroll
  for (int k = 0; k < 16; k++){
    float4 p = bufp[SWP(base2 + (k << 4))];
    a[k]  = cfmk(p.x, p.y);
    bb[k] = cfmk(p.z, p.w);
  }
  ffts16(a); ffts16(bb);
  #pragma unroll
  for (int q = 0; q < 16; q++){
    int d = R16[q];
    cf va = a[q], vb = bb[q];
    if (d){ cf tv = tw32[(m * d) << 4]; va = cfmul(va, tv); vb = cfmul(vb, tv); }
    bufp[SWP(base2 + (d << 4))] = make_float4(va.x, va.y, vb.x, vb.y);
  }
  wsync();
  // T3 + chat + invT3 fused in registers (stride 1)
  #pragma unroll
  for (int k = 0; k < 16; k++){
    float4 p = bufp[SWP(base3 + k)];
    a[k]  = cfmk(p.x, p.y);
    bb[k] = cfmk(p.z, p.w);
  }
  ffts16(a); ffts16(bb);
  #pragma unroll
  for (int q = 0; q < 16; q++){
    cf ch = chatp[(R16[q] << 8) | t];
    a[q] = cfmul(a[q], ch);
    bb[q] = cfmul(bb[q], ch);
  }
  iffts16(a); iffts16(bb);
  #pragma unroll
  for (int k = 0; k < 16; k++)
    bufp[SWP(base3 + k)] = make_float4(a[k].x, a[k].y, bb[k].x, bb[k].y);
  wsync();
  // invT2 (wave-local)
  #pragma unroll
  for (int q = 0; q < 16; q++){
    int d = R16[q];
    float4 p = bufp[SWP(base2 + (d << 4))];
    cf va = cfmk(p.x, p.y), vb = cfmk(p.z, p.w);
    if (d){ cf tv = tw32[(m * d) << 4]; va = cfmulc(va, tv); vb = cfmulc(vb, tv); }
    a[q] = va; bb[q] = vb;
  }
  iffts16(a); iffts16(bb);
  #pragma unroll
  for (int k = 0; k < 16; k++)
    bufp[SWP(base2 + (k << 4))] = make_float4(a[k].x, a[k].y, bb[k].x, bb[k].y);
  __syncthreads();
  // invT1: outputs r = t + 256j, j<8 (r < 2048); pruned iffts16h; product (fp64) + g2 + store
  #pragma unroll
  for (int q = 0; q < 16; q++){
    int d = R16[q];
    float4 p = bufp[SWP(t + (d << 8))];
    cf va = cfmk(p.x, p.y), vb = cfmk(p.z, p.w);
    if (d){ cf tv = tw32[t * d]; va = cfmulc(va, tv); vb = cfmulc(vb, tv); }
    a[q] = va; bb[q] = vb;
  }
  iffts16h(a); iffts16h(bb);
  size_t rb = ((size_t)(pair * (NB * 9) + bc) << 11);
  #pragma unroll
  for (int j = 0; j < 8; j++){
    int r = t + (j << 8);
    double ax = (double)a[j].x, ay = (double)a[j].y;
    double bx = (double)bb[j].x, by = (double)bb[j].y;
    double prx = ax * bx - ay * by;
    double pry = ax * by + ay * bx;
    cpx g = g2[r];
    Rst[rb + r] = (float)(prx * g.x - pry * g.y);
  }
}

// ---------- K5: combine pair partials + transpose [b][c][r] -> out[b][r][c]
__global__ __launch_bounds__(256) void k_out(const float* Rst, float* out){
  __shared__ float ld[9][513];
  int b = blockIdx.x >> 2;
  int r0 = (blockIdx.x & 3) << 9;
  for (int idx = threadIdx.x; idx < 9 * 512; idx += 256){
    int cc = idx >> 9, r = idx & 511;
    size_t o0 = ((size_t)(b * 9 + cc) << 11) + r0 + r;
    ld[cc][r] = Rst[o0] + Rst[o0 + ((size_t)(NB * 9) << 11)];
  }
  __syncthreads();
  for (int idx = threadIdx.x; idx < 512 * 9; idx += 256){
    int r = idx / 9, cc = idx - 9 * r;
    out[((size_t)b * TN + r0 + r) * 9 + cc] = ld[cc][r];
  }
}

extern "C" void kernel_launch(void* const* d_in, const int* in_sizes, int n_in,
                              void* d_out, int out_size, void* d_ws, size_t ws_size,
                              hipStream_t stream){
  const float* x  = (const float*)d_in[0];
  const float* A1 = (const float*)d_in[1];
  const float* A2 = (const float*)d_in[2];
  const float* fpar[16];
  for (int i = 0; i < 16; i++) fpar[i] = (const float*)d_in[3 + i];
  float* out = (float*)d_out;

  // workspace carve (units: doubles; cf = 1 double-slot), total ~19 MB
  double* ws = (double*)d_ws;
  size_t o = 0;
  double* arr  = ws + o;         o += 4 * TN;
  cf* HsQ      = (cf*)(ws + o);  o += 4 * TN;                    // 4 rows x TN, fp32
  cpx* tw      = (cpx*)(ws + o); o += 2 * NF;                    // fp64 (k_front/k_fft_u)
  cf* tw32     = (cf*)(ws + o);  o += NF;                        // fp32 (k_czt)
  cf* chatp    = (cf*)(ws + o);  o += NF;                        // fp32 (k_czt)
  cpx* Q       = (cpx*)(ws + o); o += 2 * TN;
  cpx* g2      = (cpx*)(ws + o); o += 2 * TN;
  double* Asc  = ws + o;         o += (size_t)NB * TN * 9;       // 9.4 MB
  cf* U        = (cf*)(ws + o);  o += (size_t)NB * 9 * TN;       // 9.4 MB (fp32)
  float* Rst   = (float*)Asc;    // Asc dead after k_fft_u; 2*576*2048*4B = 9.4 MB exact fit

  k_prep<<<32, 256, 0, stream>>>(fpar[0], fpar[1], fpar[2], fpar[3],
                                 fpar[4], fpar[5], fpar[6], fpar[7],
                                 fpar[8], fpar[9], fpar[10], fpar[11],
                                 fpar[12], fpar[13], fpar[14], fpar[15],
                                 arr, tw, tw32, Q, g2);
  k_front<<<321, 256, 0, stream>>>(x, A1, A2, arr, Q, tw, HsQ, Asc, chatp);
  k_fft_u<<<NB * 5, 256, 0, stream>>>(Asc, tw, U);
  k_czt<<<NB * 9 * 2, 256, 0, stream>>>(U, HsQ, tw32, chatp, g2, Rst);
  k_out<<<NB * 4, 256, 0, stream>>>(Rst, out);
}